// Round 9
// baseline (204.602 us; speedup 1.0000x reference)
//
#include <hip/hip_runtime.h>
#include <hip/hip_bf16.h>
#include <stdint.h>

#define TT 2048
#define BB 2
#define CC 1024
#define NEGF (-1e30f)

typedef short bf16x8 __attribute__((ext_vector_type(8)));
typedef short bf16x4 __attribute__((ext_vector_type(4)));
typedef float f32x4 __attribute__((ext_vector_type(4)));

__device__ __forceinline__ f32x4 mfma16(bf16x8 a, bf16x8 b, f32x4 c) {
  return __builtin_amdgcn_mfma_f32_16x16x32_bf16(a, b, c, 0, 0, 0);
}

__device__ __forceinline__ uint16_t f2bf(float f) {
  union { float f; uint32_t u; } v; v.f = f;
  uint32_t u = v.u;
  return (uint16_t)((u + 0x7FFFu + ((u >> 16) & 1u)) >> 16);
}

typedef __attribute__((address_space(3))) uint32_t lds_u32;
typedef const __attribute__((address_space(1))) uint32_t glb_u32;
__device__ __forceinline__ void gload_lds16(const uint16_t* g, uint16_t* l) {
  __builtin_amdgcn_global_load_lds((glb_u32*)g, (lds_u32*)l, 16, 0, 0);
}

// ---- x f32 -> bf16 ----
__global__ __launch_bounds__(256) void k_convert(const float* __restrict__ in,
                                                 uint16_t* __restrict__ out, int n4) {
  int i = blockIdx.x * blockDim.x + threadIdx.x;
  if (i >= n4) return;
  float4 f = ((const float4*)in)[i];
  ushort4 o;
  o.x = f2bf(f.x); o.y = f2bf(f.y); o.z = f2bf(f.z); o.w = f2bf(f.w);
  ((ushort4*)out)[i] = o;
}

// ---- W [K][N] f32 -> Wt [N][K] bf16 (LDS-tiled transpose) ----
__global__ __launch_bounds__(256) void k_transpose(const float* __restrict__ W,
                                                   uint16_t* __restrict__ Wt,
                                                   int K, int N) {
  __shared__ float tile[32][33];
  int tx = threadIdx.x & 31, ty = threadIdx.x >> 5;
  int n0 = blockIdx.x * 32, k0 = blockIdx.y * 32;
#pragma unroll
  for (int r = 0; r < 4; r++)
    tile[ty + r * 8][tx] = W[(size_t)(k0 + ty + r * 8) * N + n0 + tx];
  __syncthreads();
#pragma unroll
  for (int r = 0; r < 4; r++)
    Wt[(size_t)(n0 + ty + r * 8) * K + k0 + tx] = f2bf(tile[tx][ty + r * 8]);
}

// ---- GEMM (m97 structure): C[M][ldc] = A[M][K] * Bt[N][K]^T ----
template <bool F32OUT>
__global__ __launch_bounds__(256) void k_gemm128(const uint16_t* __restrict__ A,
                                                 const uint16_t* __restrict__ Bt,
                                                 void* __restrict__ Cp,
                                                 int K, int ldc) {
  __shared__ __align__(16) uint16_t Alds[128 * 32];
  __shared__ __align__(16) uint16_t Blds[128 * 32];
  const int tid = threadIdx.x;
  const int lane = tid & 63, wave = tid >> 6;
  const int lr = lane & 15, lg = lane >> 4;
  const int wm = wave & 1, wn = wave >> 1;
  const int m0 = blockIdx.y * 128;
  const int n0 = blockIdx.x * 128;

  f32x4 acc[4][4] = {};

  const int srow = wave * 16 + (lane >> 2);
  const int scol = (lane & 3) * 8;
  const uint16_t* pa_l = A + (size_t)(m0 + srow) * K + scol;
  const uint16_t* pb_l = Bt + (size_t)(n0 + srow) * K + scol;
  uint16_t* alds_w0 = &Alds[(wave * 64) * 8];
  uint16_t* alds_w1 = &Alds[(256 + wave * 64) * 8];
  uint16_t* blds_w0 = &Blds[(wave * 64) * 8];
  uint16_t* blds_w1 = &Blds[(256 + wave * 64) * 8];

  for (int k0 = 0; k0 < K; k0 += 32) {
    __syncthreads();
    gload_lds16(pa_l + k0, alds_w0);
    gload_lds16(pa_l + (size_t)64 * K + k0, alds_w1);
    gload_lds16(pb_l + k0, blds_w0);
    gload_lds16(pb_l + (size_t)64 * K + k0, blds_w1);
    __syncthreads();

    bf16x8 af[4], bfr[4];
#pragma unroll
    for (int mi = 0; mi < 4; mi++)
      af[mi] = *(const bf16x8*)&Alds[(wm * 64 + mi * 16 + lr) * 32 + lg * 8];
#pragma unroll
    for (int ni = 0; ni < 4; ni++)
      bfr[ni] = *(const bf16x8*)&Blds[(wn * 64 + ni * 16 + lr) * 32 + lg * 8];
#pragma unroll
    for (int mi = 0; mi < 4; mi++)
#pragma unroll
      for (int ni = 0; ni < 4; ni++)
        acc[mi][ni] = mfma16(af[mi], bfr[ni], acc[mi][ni]);
  }

#pragma unroll
  for (int mi = 0; mi < 4; mi++)
#pragma unroll
    for (int ni = 0; ni < 4; ni++)
#pragma unroll
      for (int r = 0; r < 4; r++) {
        size_t idx = (size_t)(m0 + wm * 64 + mi * 16 + lg * 4 + r) * ldc
                   + n0 + wn * 64 + ni * 16 + lr;
        if (F32OUT) ((float*)Cp)[idx] = acc[mi][ni][r];
        else        ((uint16_t*)Cp)[idx] = f2bf(acc[mi][ni][r]);
      }
}

// ---- V columns of QKV -> Vt[(b*16+h)][dv=64][t=2048] bf16 ----
__global__ __launch_bounds__(256) void k_vtrans(const uint16_t* __restrict__ QKV,
                                                uint16_t* __restrict__ Vt) {
  __shared__ uint16_t tile[64][72];
  int t0 = blockIdx.x * 64;
  int h = blockIdx.y, b = blockIdx.z;
  int vOff = (h < 8) ? (1024 + h * 64) : (2048 + (h - 8) * 64);
  const uint16_t* src = QKV + ((size_t)b * TT + t0) * 2560 + vOff;
  int tx = threadIdx.x & 15, ty = threadIdx.x >> 4;
#pragma unroll
  for (int p = 0; p < 4; p++)
    *(ushort4*)&tile[ty + p * 16][tx * 4] =
        *(const ushort4*)(src + (size_t)(ty + p * 16) * 2560 + tx * 4);
  __syncthreads();
  uint16_t* dst = Vt + ((size_t)(b * 16 + h) * 64) * TT + t0;
#pragma unroll
  for (int p = 0; p < 4; p++) {
    int dv = ty + p * 16;
    ushort4 o;
    o.x = tile[tx * 4 + 0][dv];
    o.y = tile[tx * 4 + 1][dv];
    o.z = tile[tx * 4 + 2][dv];
    o.w = tile[tx * 4 + 3][dv];
    *(ushort4*)(dst + (size_t)dv * TT + tx * 4) = o;
  }
}

// ---- windowed causal flash attention ----
// KVBLK=64, double-buffered LDS staging (T3 2-phase: stage(t+1) || compute(t),
// vmcnt(0)+raw-barrier once per tile), XOR chunk-swizzle both sides, setprio
// around MFMA clusters (T5).
__global__ __launch_bounds__(256) void k_attn(const uint16_t* __restrict__ QKV,
                                              const uint16_t* __restrict__ Vt,
                                              uint16_t* __restrict__ Y) {
  __shared__ __align__(16) uint16_t Klds[2][64 * 64];
  __shared__ __align__(16) uint16_t Vlds[2][64 * 64];
  __shared__ __align__(16) uint16_t Plds[4][16][72];
  const int tid = threadIdx.x;
  const int lane = tid & 63, wave = tid >> 6;
  const int lr = lane & 15, lg = lane >> 4;
  const int qt = blockIdx.x & 31;
  const int h = (blockIdx.x >> 5) & 15;
  const int b = blockIdx.x >> 9;
  const int q0b = qt * 64;
  const int q0 = q0b + wave * 16;

  int dqk, window, qOff, kOff;
  if (h < 8) { dqk = 64; window = 1024; qOff = h * 64; kOff = 512 + h * 64; }
  else { int hr = h - 8; dqk = 32; window = 256; qOff = 1536 + hr * 32; kOff = 1792 + hr * 32; }
  const float scale = (dqk == 64) ? 0.125f : 0.17677669529663687f;
  const uint16_t* base = QKV + (size_t)b * TT * 2560;
  const uint16_t* vt = Vt + ((size_t)(b * 16 + h) * 64) * TT;
  const int nf = dqk >> 5;

  bf16x8 qf[2];
  for (int s = 0; s < nf; s++)
    qf[s] = *(const bf16x8*)(base + (size_t)(q0 + lr) * 2560 + qOff + s * 32 + lg * 8);

  float m = NEGF, lsum = 0.f;
  f32x4 o[4] = {};

  int klo_b = q0b - window + 1; if (klo_b < 0) klo_b = 0; klo_b &= ~63;
  const int klo_w = (q0 - window + 1 < 0) ? 0 : (q0 - window + 1);
  const int khi_w = q0 + 15;
  const int q = q0 + lr;
  const int kend = q0b + 63;

  auto stage = [&](int k0, int buf) {
    if (nf == 2) {
#pragma unroll
      for (int j = 0; j < 2; j++) {
        int c = j * 256 + tid;
        int row = c >> 3, cl = c & 7, sc = cl ^ (row & 7);
        gload_lds16(base + (size_t)(k0 + row) * 2560 + kOff + sc * 8,
                    &Klds[buf][(j * 256 + wave * 64) * 8]);
      }
    } else {
      int row = tid >> 2, cl = tid & 3, sc = cl ^ (row & 3);
      gload_lds16(base + (size_t)(k0 + row) * 2560 + kOff + sc * 8,
                  &Klds[buf][(wave * 64) * 8]);
    }
#pragma unroll
    for (int j = 0; j < 2; j++) {
      int c = j * 256 + tid;
      int row = c >> 3, cl = c & 7, sc = cl ^ (row & 7);
      gload_lds16(vt + (size_t)row * TT + k0 + sc * 8,
                  &Vlds[buf][(j * 256 + wave * 64) * 8]);
    }
  };

  // prologue: stage tile 0, drain, barrier
  stage(klo_b, 0);
  asm volatile("s_waitcnt vmcnt(0)" ::: "memory");
  __builtin_amdgcn_s_barrier();
  __builtin_amdgcn_sched_barrier(0);

  int cur = 0;
  for (int k0 = klo_b; k0 <= kend; k0 += 64) {
    // issue next tile's staging into the other buffer (freed by last barrier)
    const int nxt = k0 + 64;
    if (nxt <= kend) stage(nxt, cur ^ 1);

    if (!(k0 > khi_w || k0 + 63 < klo_w)) {
      // ---- S^T = K·Q^T over 4 key-halves ----
      f32x4 st[4];
      __builtin_amdgcn_s_setprio(1);
#pragma unroll
      for (int hh = 0; hh < 4; hh++) {
        f32x4 acc = {0.f, 0.f, 0.f, 0.f};
        int row = hh * 16 + lr;
        if (nf == 2) {
          acc = mfma16(*(const bf16x8*)&Klds[cur][row * 64 + ((lg) ^ (row & 7)) * 8], qf[0], acc);
          acc = mfma16(*(const bf16x8*)&Klds[cur][row * 64 + ((4 + lg) ^ (row & 7)) * 8], qf[1], acc);
        } else {
          acc = mfma16(*(const bf16x8*)&Klds[cur][row * 32 + ((lg) ^ (row & 3)) * 8], qf[0], acc);
        }
        st[hh] = acc;
      }
      __builtin_amdgcn_s_setprio(0);
      // ---- scale + window mask ----
      float tmax = NEGF;
      const bool interior = (k0 + 63 <= q0) && (q0 + 15 - k0 < window);
      if (interior) {
#pragma unroll
        for (int hh = 0; hh < 4; hh++)
#pragma unroll
          for (int r = 0; r < 4; r++) {
            float sv = st[hh][r] * scale;
            st[hh][r] = sv;
            tmax = fmaxf(tmax, sv);
          }
      } else {
#pragma unroll
        for (int hh = 0; hh < 4; hh++)
#pragma unroll
          for (int r = 0; r < 4; r++) {
            int key = k0 + 16 * hh + lg * 4 + r;
            bool ok = (key <= q) && (q - key < window);
            float sv = ok ? st[hh][r] * scale : NEGF;
            st[hh][r] = sv;
            tmax = fmaxf(tmax, sv);
          }
      }
      tmax = fmaxf(tmax, __shfl_xor(tmax, 16));
      tmax = fmaxf(tmax, __shfl_xor(tmax, 32));
      // ---- online softmax (skip rescale when no row's max grew) ----
      if (!__all(tmax <= m)) {
        float mn = fmaxf(m, tmax);
        float alpha = __expf(m - mn);
        lsum *= alpha;
#pragma unroll
        for (int d = 0; d < 4; d++) o[d] *= alpha;
        m = mn;
      }
      float psum = 0.f;
#pragma unroll
      for (int hh = 0; hh < 4; hh++) {
        bf16x4 pk;
#pragma unroll
        for (int r = 0; r < 4; r++) {
          float sv = st[hh][r];
          float p = (sv > -0.5e30f) ? __expf(sv - m) : 0.f;
          psum += p;
          pk[r] = (short)f2bf(p);
        }
        *(bf16x4*)&Plds[wave][lr][16 * hh + lg * 4] = pk;
      }
      psum += __shfl_xor(psum, 16);
      psum += __shfl_xor(psum, 32);
      lsum += psum;

      // ---- O^T += V^T·P^T over 2 key-slices ----
      __builtin_amdgcn_s_setprio(1);
#pragma unroll
      for (int ks = 0; ks < 2; ks++) {
        bf16x8 pf = *(const bf16x8*)&Plds[wave][lr][ks * 32 + lg * 8];
#pragma unroll
        for (int db = 0; db < 4; db++) {
          int row = db * 16 + lr;
          bf16x8 vf = *(const bf16x8*)&Vlds[cur][row * 64 + ((4 * ks + lg) ^ (row & 7)) * 8];
          o[db] = mfma16(vf, pf, o[db]);
        }
      }
      __builtin_amdgcn_s_setprio(0);
    }

    // tile boundary: next tile's loads must be landed; all waves done reading
    asm volatile("s_waitcnt vmcnt(0)" ::: "memory");
    __builtin_amdgcn_sched_barrier(0);
    __builtin_amdgcn_s_barrier();
    __builtin_amdgcn_sched_barrier(0);
    cur ^= 1;
  }
  // ---- epilogue ----
  const float inv = 1.0f / lsum;
  uint16_t* yp = Y + ((size_t)b * TT + q0 + lr) * CC + h * 64;
#pragma unroll
  for (int db = 0; db < 4; db++)
#pragma unroll
    for (int r = 0; r < 4; r++)
      yp[db * 16 + lg * 4 + r] = f2bf(o[db][r] * inv);
}

extern "C" void kernel_launch(void* const* d_in, const int* in_sizes, int n_in,
                              void* d_out, int out_size, void* d_ws, size_t ws_size,
                              hipStream_t stream) {
  const float* x    = (const float*)d_in[0];
  const float* wqkv = (const float*)d_in[1];
  const float* wqk  = (const float*)d_in[2];
  const float* wv   = (const float*)d_in[3];
  const float* wp   = (const float*)d_in[4];

  uint16_t* ws  = (uint16_t*)d_ws;
  uint16_t* xb  = ws;                               // [4096][1024] (dead after QKV GEMM)
  uint16_t* WtA = xb  + (size_t)4096 * 1024;        // [2560][1024]
  uint16_t* WtP = WtA + (size_t)2560 * 1024;        // [1024][1024]
  uint16_t* QKV = WtP + (size_t)1024 * 1024;        // [4096][2560]
  uint16_t* Yb  = QKV + (size_t)4096 * 2560;        // [4096][1024]
  uint16_t* Vt  = xb;                               // alias after GEMM: [32][64][2048]

  k_convert<<<4096, 256, 0, stream>>>(x, xb, 4096 * 1024 / 4);
  k_transpose<<<dim3(48, 32), 256, 0, stream>>>(wqkv, WtA, 1024, 1536);
  k_transpose<<<dim3(16, 32), 256, 0, stream>>>(wqk, WtA + (size_t)1536 * 1024, 1024, 512);
  k_transpose<<<dim3(16, 32), 256, 0, stream>>>(wv,  WtA + (size_t)2048 * 1024, 1024, 512);
  k_transpose<<<dim3(32, 32), 256, 0, stream>>>(wp,  WtP, 1024, 1024);
  k_gemm128<false><<<dim3(20, 32), 256, 0, stream>>>(xb, WtA, QKV, 1024, 2560);
  k_vtrans<<<dim3(32, 16, 2), 256, 0, stream>>>(QKV, Vt);
  k_attn<<<1024, 256, 0, stream>>>(QKV, Vt, Yb);
  k_gemm128<true><<<dim3(8, 32), 256, 0, stream>>>(Yb, WtP, (float*)d_out, 1024, 1024);
}

// Round 10
// 189.256 us; speedup vs baseline: 1.0811x; 1.0811x over previous
//
#include <hip/hip_runtime.h>
#include <hip/hip_bf16.h>
#include <stdint.h>

#define TT 2048
#define BB 2
#define CC 1024
#define NEGF (-1e30f)

typedef short bf16x8 __attribute__((ext_vector_type(8)));
typedef short bf16x4 __attribute__((ext_vector_type(4)));
typedef float f32x4 __attribute__((ext_vector_type(4)));

__device__ __forceinline__ f32x4 mfma16(bf16x8 a, bf16x8 b, f32x4 c) {
  return __builtin_amdgcn_mfma_f32_16x16x32_bf16(a, b, c, 0, 0, 0);
}

__device__ __forceinline__ uint16_t f2bf(float f) {   // RNE
  union { float f; uint32_t u; } v; v.f = f;
  uint32_t u = v.u;
  return (uint16_t)((u + 0x7FFFu + ((u >> 16) & 1u)) >> 16);
}
__device__ __forceinline__ uint16_t f2bf_fast(float f) {  // round-half-up (p>=0 finite)
  union { float f; uint32_t u; } v; v.f = f;
  return (uint16_t)((v.u + 0x8000u) >> 16);
}

typedef __attribute__((address_space(3))) uint32_t lds_u32;
typedef const __attribute__((address_space(1))) uint32_t glb_u32;
__device__ __forceinline__ void gload_lds16(const uint16_t* g, uint16_t* l) {
  __builtin_amdgcn_global_load_lds((glb_u32*)g, (lds_u32*)l, 16, 0, 0);
}

// ---- x f32 -> bf16 ----
__global__ __launch_bounds__(256) void k_convert(const float* __restrict__ in,
                                                 uint16_t* __restrict__ out, int n4) {
  int i = blockIdx.x * blockDim.x + threadIdx.x;
  if (i >= n4) return;
  float4 f = ((const float4*)in)[i];
  ushort4 o;
  o.x = f2bf(f.x); o.y = f2bf(f.y); o.z = f2bf(f.z); o.w = f2bf(f.w);
  ((ushort4*)out)[i] = o;
}

// ---- W [K][N] f32 -> Wt [N][K] bf16 (LDS-tiled transpose) ----
__global__ __launch_bounds__(256) void k_transpose(const float* __restrict__ W,
                                                   uint16_t* __restrict__ Wt,
                                                   int K, int N) {
  __shared__ float tile[32][33];
  int tx = threadIdx.x & 31, ty = threadIdx.x >> 5;
  int n0 = blockIdx.x * 32, k0 = blockIdx.y * 32;
#pragma unroll
  for (int r = 0; r < 4; r++)
    tile[ty + r * 8][tx] = W[(size_t)(k0 + ty + r * 8) * N + n0 + tx];
  __syncthreads();
#pragma unroll
  for (int r = 0; r < 4; r++)
    Wt[(size_t)(n0 + ty + r * 8) * K + k0 + tx] = f2bf(tile[tx][ty + r * 8]);
}

// ---- GEMM (2-phase dbuf): C[M][ldc] = A[M][K] * Bt[N][K]^T ----
// 128x128 tile, BK=32, 4 waves (2x2). stage(t+1) || compute(t), vmcnt(0)+barrier.
template <bool F32OUT>
__global__ __launch_bounds__(256) void k_gemm128(const uint16_t* __restrict__ A,
                                                 const uint16_t* __restrict__ Bt,
                                                 void* __restrict__ Cp,
                                                 int K, int ldc) {
  __shared__ __align__(16) uint16_t Alds[2][128 * 32];
  __shared__ __align__(16) uint16_t Blds[2][128 * 32];
  const int tid = threadIdx.x;
  const int lane = tid & 63, wave = tid >> 6;
  const int lr = lane & 15, lg = lane >> 4;
  const int wm = wave & 1, wn = wave >> 1;
  const int m0 = blockIdx.y * 128;
  const int n0 = blockIdx.x * 128;

  f32x4 acc[4][4] = {};

  const int srow = wave * 16 + (lane >> 2);
  const int scol = (lane & 3) * 8;
  const uint16_t* pa_l = A + (size_t)(m0 + srow) * K + scol;
  const uint16_t* pb_l = Bt + (size_t)(n0 + srow) * K + scol;

  auto stage = [&](int k0, int buf) {
    gload_lds16(pa_l + k0, &Alds[buf][(wave * 64) * 8]);
    gload_lds16(pa_l + (size_t)64 * K + k0, &Alds[buf][(256 + wave * 64) * 8]);
    gload_lds16(pb_l + k0, &Blds[buf][(wave * 64) * 8]);
    gload_lds16(pb_l + (size_t)64 * K + k0, &Blds[buf][(256 + wave * 64) * 8]);
  };

  stage(0, 0);
  asm volatile("s_waitcnt vmcnt(0)" ::: "memory");
  __builtin_amdgcn_s_barrier();
  __builtin_amdgcn_sched_barrier(0);

  int cur = 0;
  for (int k0 = 0; k0 < K; k0 += 32) {
    if (k0 + 32 < K) stage(k0 + 32, cur ^ 1);

    bf16x8 af[4], bfr[4];
#pragma unroll
    for (int mi = 0; mi < 4; mi++)
      af[mi] = *(const bf16x8*)&Alds[cur][(wm * 64 + mi * 16 + lr) * 32 + lg * 8];
#pragma unroll
    for (int ni = 0; ni < 4; ni++)
      bfr[ni] = *(const bf16x8*)&Blds[cur][(wn * 64 + ni * 16 + lr) * 32 + lg * 8];
#pragma unroll
    for (int mi = 0; mi < 4; mi++)
#pragma unroll
      for (int ni = 0; ni < 4; ni++)
        acc[mi][ni] = mfma16(af[mi], bfr[ni], acc[mi][ni]);

    asm volatile("s_waitcnt vmcnt(0)" ::: "memory");
    __builtin_amdgcn_sched_barrier(0);
    __builtin_amdgcn_s_barrier();
    __builtin_amdgcn_sched_barrier(0);
    cur ^= 1;
  }

#pragma unroll
  for (int mi = 0; mi < 4; mi++)
#pragma unroll
    for (int ni = 0; ni < 4; ni++)
#pragma unroll
      for (int r = 0; r < 4; r++) {
        size_t idx = (size_t)(m0 + wm * 64 + mi * 16 + lg * 4 + r) * ldc
                   + n0 + wn * 64 + ni * 16 + lr;
        if (F32OUT) ((float*)Cp)[idx] = acc[mi][ni][r];
        else        ((uint16_t*)Cp)[idx] = f2bf(acc[mi][ni][r]);
      }
}

// ---- V columns of QKV -> Vt[(b*16+h)][dv=64][t=2048] bf16 ----
__global__ __launch_bounds__(256) void k_vtrans(const uint16_t* __restrict__ QKV,
                                                uint16_t* __restrict__ Vt) {
  __shared__ uint16_t tile[64][72];
  int t0 = blockIdx.x * 64;
  int h = blockIdx.y, b = blockIdx.z;
  int vOff = (h < 8) ? (1024 + h * 64) : (2048 + (h - 8) * 64);
  const uint16_t* src = QKV + ((size_t)b * TT + t0) * 2560 + vOff;
  int tx = threadIdx.x & 15, ty = threadIdx.x >> 4;
#pragma unroll
  for (int p = 0; p < 4; p++)
    *(ushort4*)&tile[ty + p * 16][tx * 4] =
        *(const ushort4*)(src + (size_t)(ty + p * 16) * 2560 + tx * 4);
  __syncthreads();
  uint16_t* dst = Vt + ((size_t)(b * 16 + h) * 64) * TT + t0;
#pragma unroll
  for (int p = 0; p < 4; p++) {
    int dv = ty + p * 16;
    ushort4 o;
    o.x = tile[tx * 4 + 0][dv];
    o.y = tile[tx * 4 + 1][dv];
    o.z = tile[tx * 4 + 2][dv];
    o.w = tile[tx * 4 + 3][dv];
    *(ushort4*)(dst + (size_t)dv * TT + tx * 4) = o;
  }
}

// ---- windowed causal flash attention ----
// KVBLK=64, dbuf staging, XOR chunk-swizzle, setprio on MFMA clusters,
// raw-score softmax: one fma + exp2 per element, LPT block ordering.
__global__ __launch_bounds__(256) void k_attn(const uint16_t* __restrict__ QKV,
                                              const uint16_t* __restrict__ Vt,
                                              uint16_t* __restrict__ Y) {
  __shared__ __align__(16) uint16_t Klds[2][64 * 64];
  __shared__ __align__(16) uint16_t Vlds[2][64 * 64];
  __shared__ __align__(16) uint16_t Plds[4][16][72];
  const int tid = threadIdx.x;
  const int lane = tid & 63, wave = tid >> 6;
  const int lr = lane & 15, lg = lane >> 4;

  // LPT remap: full heads (17..1 tiles) qt-descending first, reduced last.
  int idx = blockIdx.x, b, h, qt;
  if (idx < 512) { qt = 31 - (idx >> 4); h = (idx >> 1) & 7; b = idx & 1; }
  else { int j = idx - 512; qt = 31 - (j >> 4); h = 8 + ((j >> 1) & 7); b = j & 1; }
  const int q0b = qt * 64;
  const int q0 = q0b + wave * 16;

  int dqk, window, qOff, kOff;
  if (h < 8) { dqk = 64; window = 1024; qOff = h * 64; kOff = 512 + h * 64; }
  else { int hr = h - 8; dqk = 32; window = 256; qOff = 1536 + hr * 32; kOff = 1792 + hr * 32; }
  const float scale = (dqk == 64) ? 0.125f : 0.17677669529663687f;
  const float cl2 = scale * 1.44269504f;       // fold scale*log2e into exp2-fma
  const uint16_t* base = QKV + (size_t)b * TT * 2560;
  const uint16_t* vt = Vt + ((size_t)(b * 16 + h) * 64) * TT;
  const int nf = dqk >> 5;

  bf16x8 qf[2];
  for (int s = 0; s < nf; s++)
    qf[s] = *(const bf16x8*)(base + (size_t)(q0 + lr) * 2560 + qOff + s * 32 + lg * 8);

  float m = NEGF, lsum = 0.f;                  // m tracks RAW (unscaled) max
  f32x4 o[4] = {};

  int klo_b = q0b - window + 1; if (klo_b < 0) klo_b = 0; klo_b &= ~63;
  const int klo_w = (q0 - window + 1 < 0) ? 0 : (q0 - window + 1);
  const int khi_w = q0 + 15;
  const int q = q0 + lr;
  const int kend = q0b + 63;

  auto stage = [&](int k0, int buf) {
    if (nf == 2) {
#pragma unroll
      for (int j = 0; j < 2; j++) {
        int c = j * 256 + tid;
        int row = c >> 3, cl = c & 7, sc = cl ^ (row & 7);
        gload_lds16(base + (size_t)(k0 + row) * 2560 + kOff + sc * 8,
                    &Klds[buf][(j * 256 + wave * 64) * 8]);
      }
    } else {
      int row = tid >> 2, cl = tid & 3, sc = cl ^ (row & 3);
      gload_lds16(base + (size_t)(k0 + row) * 2560 + kOff + sc * 8,
                  &Klds[buf][(wave * 64) * 8]);
    }
#pragma unroll
    for (int j = 0; j < 2; j++) {
      int c = j * 256 + tid;
      int row = c >> 3, cl = c & 7, sc = cl ^ (row & 7);
      gload_lds16(vt + (size_t)row * TT + k0 + sc * 8,
                  &Vlds[buf][(j * 256 + wave * 64) * 8]);
    }
  };

  stage(klo_b, 0);
  asm volatile("s_waitcnt vmcnt(0)" ::: "memory");
  __builtin_amdgcn_s_barrier();
  __builtin_amdgcn_sched_barrier(0);

  int cur = 0;
  for (int k0 = klo_b; k0 <= kend; k0 += 64) {
    const int nxt = k0 + 64;
    if (nxt <= kend) stage(nxt, cur ^ 1);

    if (!(k0 > khi_w || k0 + 63 < klo_w)) {
      // ---- S^T = K·Q^T (raw scores) ----
      f32x4 st[4];
      __builtin_amdgcn_s_setprio(1);
#pragma unroll
      for (int hh = 0; hh < 4; hh++) {
        f32x4 acc = {0.f, 0.f, 0.f, 0.f};
        int row = hh * 16 + lr;
        if (nf == 2) {
          acc = mfma16(*(const bf16x8*)&Klds[cur][row * 64 + ((lg) ^ (row & 7)) * 8], qf[0], acc);
          acc = mfma16(*(const bf16x8*)&Klds[cur][row * 64 + ((4 + lg) ^ (row & 7)) * 8], qf[1], acc);
        } else {
          acc = mfma16(*(const bf16x8*)&Klds[cur][row * 32 + ((lg) ^ (row & 3)) * 8], qf[0], acc);
        }
        st[hh] = acc;
      }
      __builtin_amdgcn_s_setprio(0);
      // ---- window mask on raw scores (no scale mul) ----
      const bool interior = (k0 + 63 <= q0) && (q0 + 15 - k0 < window);
      if (!interior) {
#pragma unroll
        for (int hh = 0; hh < 4; hh++)
#pragma unroll
          for (int r = 0; r < 4; r++) {
            int key = k0 + 16 * hh + lg * 4 + r;
            bool ok = (key <= q) && (q - key < window);
            st[hh][r] = ok ? st[hh][r] : NEGF;
          }
      }
      float tmax = NEGF;
#pragma unroll
      for (int hh = 0; hh < 4; hh++) {
        float t01 = fmaxf(st[hh][0], st[hh][1]);
        float t23 = fmaxf(st[hh][2], st[hh][3]);
        tmax = fmaxf(tmax, fmaxf(t01, t23));
      }
      tmax = fmaxf(tmax, __shfl_xor(tmax, 16));
      tmax = fmaxf(tmax, __shfl_xor(tmax, 32));
      // ---- online softmax (skip rescale when no row's max grew) ----
      if (!__all(tmax <= m)) {
        float mn = fmaxf(m, tmax);
        float alpha = exp2f((m - mn) * cl2);
        lsum *= alpha;
#pragma unroll
        for (int d = 0; d < 4; d++) o[d] *= alpha;
        m = mn;
      }
      // p = exp2(raw*cl2 - mc); masked NEGF underflows to exactly 0.
      const float mc = fmaxf(m, -1e20f) * cl2;
      f32x4 ps = {0.f, 0.f, 0.f, 0.f};
#pragma unroll
      for (int hh = 0; hh < 4; hh++) {
        bf16x4 pk;
#pragma unroll
        for (int r = 0; r < 4; r++) {
          float p = exp2f(__builtin_fmaf(st[hh][r], cl2, -mc));
          ps[r] += p;
          pk[r] = (short)f2bf_fast(p);
        }
        *(bf16x4*)&Plds[wave][lr][16 * hh + lg * 4] = pk;
      }
      float psum = (ps[0] + ps[1]) + (ps[2] + ps[3]);
      psum += __shfl_xor(psum, 16);
      psum += __shfl_xor(psum, 32);
      lsum += psum;

      // ---- O^T += V^T·P^T ----
      __builtin_amdgcn_s_setprio(1);
#pragma unroll
      for (int ks = 0; ks < 2; ks++) {
        bf16x8 pf = *(const bf16x8*)&Plds[wave][lr][ks * 32 + lg * 8];
#pragma unroll
        for (int db = 0; db < 4; db++) {
          int row = db * 16 + lr;
          bf16x8 vf = *(const bf16x8*)&Vlds[cur][row * 64 + ((4 * ks + lg) ^ (row & 7)) * 8];
          o[db] = mfma16(vf, pf, o[db]);
        }
      }
      __builtin_amdgcn_s_setprio(0);
    }

    asm volatile("s_waitcnt vmcnt(0)" ::: "memory");
    __builtin_amdgcn_sched_barrier(0);
    __builtin_amdgcn_s_barrier();
    __builtin_amdgcn_sched_barrier(0);
    cur ^= 1;
  }
  // ---- epilogue ----
  const float inv = 1.0f / lsum;
  uint16_t* yp = Y + ((size_t)b * TT + q0 + lr) * CC + h * 64;
#pragma unroll
  for (int db = 0; db < 4; db++)
#pragma unroll
    for (int r = 0; r < 4; r++)
      yp[db * 16 + lg * 4 + r] = f2bf(o[db][r] * inv);
}

extern "C" void kernel_launch(void* const* d_in, const int* in_sizes, int n_in,
                              void* d_out, int out_size, void* d_ws, size_t ws_size,
                              hipStream_t stream) {
  const float* x    = (const float*)d_in[0];
  const float* wqkv = (const float*)d_in[1];
  const float* wqk  = (const float*)d_in[2];
  const float* wv   = (const float*)d_in[3];
  const float* wp   = (const float*)d_in[4];

  uint16_t* ws  = (uint16_t*)d_ws;
  uint16_t* xb  = ws;                               // [4096][1024] (dead after QKV GEMM)
  uint16_t* WtA = xb  + (size_t)4096 * 1024;        // [2560][1024]
  uint16_t* WtP = WtA + (size_t)2560 * 1024;        // [1024][1024]
  uint16_t* QKV = WtP + (size_t)1024 * 1024;        // [4096][2560]
  uint16_t* Yb  = QKV + (size_t)4096 * 2560;        // [4096][1024]
  uint16_t* Vt  = xb;                               // alias after GEMM: [32][64][2048]

  k_convert<<<4096, 256, 0, stream>>>(x, xb, 4096 * 1024 / 4);
  k_transpose<<<dim3(48, 32), 256, 0, stream>>>(wqkv, WtA, 1024, 1536);
  k_transpose<<<dim3(16, 32), 256, 0, stream>>>(wqk, WtA + (size_t)1536 * 1024, 1024, 512);
  k_transpose<<<dim3(16, 32), 256, 0, stream>>>(wv,  WtA + (size_t)2048 * 1024, 1024, 512);
  k_transpose<<<dim3(32, 32), 256, 0, stream>>>(wp,  WtP, 1024, 1024);
  k_gemm128<false><<<dim3(20, 32), 256, 0, stream>>>(xb, WtA, QKV, 1024, 2560);
  k_vtrans<<<dim3(32, 16, 2), 256, 0, stream>>>(QKV, Vt);
  k_attn<<<1024, 256, 0, stream>>>(QKV, Vt, Yb);
  k_gemm128<true><<<dim3(8, 32), 256, 0, stream>>>(Yb, WtP, (float*)d_out, 1024, 1024);
}